// Round 4
// baseline (334.224 us; speedup 1.0000x reference)
//
#include <hip/hip_runtime.h>
#include <hip/hip_bf16.h>

#define NN 8192
#define HIDD 128
#define NLAY 2

typedef __attribute__((ext_vector_type(8))) short bf16x8;
typedef __attribute__((ext_vector_type(4))) float f32x4;

static __device__ __forceinline__ unsigned short f2b(float x) {
    __hip_bfloat16 h = __float2bfloat16(x);
    return *reinterpret_cast<unsigned short*>(&h);
}

// spread bit i -> bit 4i (16-bit input)
static __device__ __forceinline__ unsigned long long spread4(unsigned long long x) {
    x = (x | (x << 24)) & 0x000000ff000000ffULL;
    x = (x | (x << 12)) & 0x000f000f000f000fULL;
    x = (x | (x << 6))  & 0x0303030303030303ULL;
    x = (x | (x << 3))  & 0x1111111111111111ULL;
    return x;
}

// ================================================================ pre-kernel
// blocks 0..511: proj (16 rows each); 512..513: wprep (l = b-512); rest: bitmask
__global__ void k_pre(const int* __restrict__ adj, unsigned long long* __restrict__ bm,
                      const float* __restrict__ hin, const float* __restrict__ Wp,
                      const float* __restrict__ bp, float* __restrict__ hout,
                      const float* __restrict__ Wk, const float* __restrict__ Wq,
                      const float* __restrict__ a1, const float* __restrict__ a2,
                      const float* __restrict__ bk, const float* __restrict__ bq,
                      float* __restrict__ wka, float* __restrict__ wqa,
                      float* __restrict__ scal) {
    __shared__ float ht[16][128];
    int b = blockIdx.x;
    int tid = threadIdx.x;
    if (b < 512) {
        // ---- proj: h0 = h @ Wp + bp
        int i0 = b * 16;
#pragma unroll
        for (int r = 0; r < 2; r++) {
            int q = r * 256 + tid;
            ((float4*)ht)[q] = ((const float4*)(hin + (size_t)i0 * 128))[q];
        }
        __syncthreads();
        int c = tid & 127, half = tid >> 7;
        float acc[8];
        float b0 = bp[c];
#pragma unroll
        for (int m = 0; m < 8; m++) acc[m] = b0;
        for (int k = 0; k < 128; k += 4) {
            float w0 = Wp[k * 128 + c], w1 = Wp[(k + 1) * 128 + c];
            float w2 = Wp[(k + 2) * 128 + c], w3 = Wp[(k + 3) * 128 + c];
#pragma unroll
            for (int m = 0; m < 8; m++) {
                float4 hv = *(const float4*)&ht[half + 2 * m][k];
                acc[m] = fmaf(hv.x, w0, acc[m]);
                acc[m] = fmaf(hv.y, w1, acc[m]);
                acc[m] = fmaf(hv.z, w2, acc[m]);
                acc[m] = fmaf(hv.w, w3, acc[m]);
            }
        }
#pragma unroll
        for (int m = 0; m < 8; m++) hout[(size_t)(i0 + half + 2 * m) * 128 + c] = acc[m];
    } else if (b < 514) {
        // ---- wprep for layer l
        int l = b - 512;
        const float* a1L = a1 + l * 128;
        const float* a2L = a2 + l * 128;
        if (tid < 128) {
            const float* W1 = Wk + (size_t)l * 16384 + (size_t)tid * 128;
            const float* W2 = Wq + (size_t)l * 16384 + (size_t)tid * 128;
            float s1 = 0.f, s2 = 0.f;
            for (int c = 0; c < 128; c++) {
                s1 = fmaf(W1[c], a1L[c], s1);
                s2 = fmaf(W2[c], a2L[c], s2);
            }
            wka[l * 128 + tid] = s1;
            wqa[l * 128 + tid] = s2;
        } else if (tid == 128) {
            float s = 0.f;
            for (int c = 0; c < 128; c++) s = fmaf(bk[l * 128 + c], a1L[c], s);
            scal[l * 2 + 0] = s;
        } else if (tid == 129) {
            float s = 0.f;
            for (int c = 0; c < 128; c++) s = fmaf(bq[l * 128 + c], a2L[c], s);
            scal[l * 2 + 1] = s;
        }
    } else {
        // ---- bitmask (16B/lane)
        const long totalg = (long)NN * (NN / 256);
        int lane = tid & 63, w = tid >> 6;
        long nb = (long)gridDim.x - 514;
        long g = (long)(b - 514) * 4 + w;
        long ng = nb * 4;
        for (; g < totalg; g += ng) {
            int4 v = ((const int4*)adj)[g * 64 + lane];
            unsigned long long B0 = __ballot(v.x > 0);
            unsigned long long B1 = __ballot(v.y > 0);
            unsigned long long B2 = __ballot(v.z > 0);
            unsigned long long B3 = __ballot(v.w > 0);
            if (lane < 4) {
                int sh = lane * 16;
                unsigned long long W = spread4((B0 >> sh) & 0xFFFF)
                                     | (spread4((B1 >> sh) & 0xFFFF) << 1)
                                     | (spread4((B2 >> sh) & 0xFFFF) << 2)
                                     | (spread4((B3 >> sh) & 0xFFFF) << 3);
                bm[g * 4 + lane] = W;
            }
        }
    }
}

// ================================================================ fused gm:
// [inline combine of prev agg] + gm compute + bf16 transpose write + kdot/qdot + loss
__global__ void k_gm(const float* __restrict__ hbase, const float* __restrict__ aggs, int nslab,
                     float* __restrict__ hstore, const float* __restrict__ z,
                     const float* __restrict__ Wm, const float* __restrict__ bmv,
                     const float* __restrict__ Wg, const float* __restrict__ bgv,
                     const float* __restrict__ wka, const float* __restrict__ wqa,
                     const float* __restrict__ scal,
                     unsigned short* __restrict__ gmT, float* __restrict__ kdot,
                     float* __restrict__ qdot, float* __restrict__ lossacc) {
    __shared__ float ht[16][128];
    __shared__ float zt[16][64];
    __shared__ unsigned short tb[128][24];   // [hid][row-local], row stride 48B (16B-aligned)
    __shared__ float redk[4][8], redq[4][8], redl[4];
    int i0 = blockIdx.x * 16;
    int tid = threadIdx.x;
    // load h rows (+ inline combine with prev-layer agg slabs)
#pragma unroll
    for (int r = 0; r < 2; r++) {
        int q = r * 256 + tid;
        float4 hv = ((const float4*)(hbase + (size_t)i0 * 128))[q];
        if (nslab > 0) {
            float sx = 0.f, sy = 0.f, sz = 0.f, sw = 0.f;
            for (int s = 0; s < nslab; s++) {
                float4 a = ((const float4*)(aggs + (size_t)s * NN * HIDD + (size_t)i0 * 128))[q];
                sx += a.x; sy += a.y; sz += a.z; sw += a.w;
            }
            hv.x = (hv.x + sx) * 0.5f;
            hv.y = (hv.y + sy) * 0.5f;
            hv.z = (hv.z + sz) * 0.5f;
            hv.w = (hv.w + sw) * 0.5f;
            ((float4*)(hstore + (size_t)i0 * 128))[q] = hv;
        }
        ((float4*)ht)[q] = hv;
    }
    ((float4*)zt)[tid] = ((const float4*)(z + (size_t)i0 * 64))[tid];
    __syncthreads();
    int c = tid & 127, half = tid >> 7;
    float am[8], ag[8];
    float bm0 = bmv[c], bg0 = bgv[c];
#pragma unroll
    for (int m = 0; m < 8; m++) { am[m] = bm0; ag[m] = bg0; }
    for (int k = 0; k < 128; k += 4) {
        float wm0 = Wm[k * 128 + c], wm1 = Wm[(k + 1) * 128 + c];
        float wm2 = Wm[(k + 2) * 128 + c], wm3 = Wm[(k + 3) * 128 + c];
        float wg0 = Wg[k * 128 + c], wg1 = Wg[(k + 1) * 128 + c];
        float wg2 = Wg[(k + 2) * 128 + c], wg3 = Wg[(k + 3) * 128 + c];
#pragma unroll
        for (int m = 0; m < 8; m++) {
            float4 hv = *(const float4*)&ht[half + 2 * m][k];
            am[m] = fmaf(hv.x, wm0, am[m]);
            am[m] = fmaf(hv.y, wm1, am[m]);
            am[m] = fmaf(hv.z, wm2, am[m]);
            am[m] = fmaf(hv.w, wm3, am[m]);
            ag[m] = fmaf(hv.x, wg0, ag[m]);
            ag[m] = fmaf(hv.y, wg1, ag[m]);
            ag[m] = fmaf(hv.z, wg2, ag[m]);
            ag[m] = fmaf(hv.w, wg3, ag[m]);
        }
    }
    for (int k = 0; k < 64; k += 4) {
        float wg0 = Wg[(128 + k) * 128 + c], wg1 = Wg[(129 + k) * 128 + c];
        float wg2 = Wg[(130 + k) * 128 + c], wg3 = Wg[(131 + k) * 128 + c];
#pragma unroll
        for (int m = 0; m < 8; m++) {
            float4 zv = *(const float4*)&zt[half + 2 * m][k];
            ag[m] = fmaf(zv.x, wg0, ag[m]);
            ag[m] = fmaf(zv.y, wg1, ag[m]);
            ag[m] = fmaf(zv.z, wg2, ag[m]);
            ag[m] = fmaf(zv.w, wg3, ag[m]);
        }
    }
    float lsum = 0.f;
    float gmv[8];
#pragma unroll
    for (int m = 0; m < 8; m++) {
        float gate = 1.f / (1.f + __expf(-ag[m]));
        lsum += gate;
        gmv[m] = gate * fmaxf(am[m], 0.f);
        tb[c][half + 2 * m] = f2b(gmv[m]);
    }
    // kdot/qdot row reductions: row r = half+2m; waves {2*half, 2*half+1} hold its 128 cols
    float wkac = wka[c], wqac = wqa[c];
    int wid = tid >> 6, lane = tid & 63;
#pragma unroll
    for (int m = 0; m < 8; m++) {
        float vk = ht[half + 2 * m][c] * wkac;
        float vq = gmv[m] * wqac;
#pragma unroll
        for (int o = 32; o; o >>= 1) {
            vk += __shfl_down(vk, o);
            vq += __shfl_down(vq, o);
        }
        if (lane == 0) { redk[wid][m] = vk; redq[wid][m] = vq; }
    }
#pragma unroll
    for (int o = 32; o; o >>= 1) lsum += __shfl_down(lsum, o);
    if (lane == 0) redl[wid] = lsum;
    __syncthreads();
    if (tid < 16) {
        int r = tid, hf = r & 1, m = r >> 1;
        const float LOG2E = 1.4426950408889634f;
        kdot[i0 + r] = (redk[2 * hf][m] + redk[2 * hf + 1][m] + scal[0]) * LOG2E;
        qdot[i0 + r] = (redq[2 * hf][m] + redq[2 * hf + 1][m] + scal[1]) * LOG2E;
    }
    if (tid == 0) atomicAdd(lossacc, redl[0] + redl[1] + redl[2] + redl[3]);
    // gmT write: thread t -> row hh = t>>1, 8 ushorts at io = (t&1)*8
    int hh = tid >> 1, io = (tid & 1) * 8;
    *(int4*)&gmT[(size_t)hh * NN + i0 + io] = *(int4*)&tb[hh][io];
}

// ---------------------------------------------------------------- coef[i] = 1/sum_j mask*exp2(lrelu2(...))
__global__ void k_stats(const unsigned* __restrict__ bm32, const float* __restrict__ kdot,
                        const float* __restrict__ qdot, float* __restrict__ coef) {
    int row = (int)((blockIdx.x * blockDim.x + threadIdx.x) >> 6);
    int lane = threadIdx.x & 63;
    const unsigned* bmr = bm32 + (size_t)row * 256;
    float qi = qdot[row];
    float s = 0.f;
    for (int t = 0; t < 32; t++) {
        int j0 = t * 256 + lane * 4;
        unsigned word = bmr[j0 >> 5];
        float4 kv = *(const float4*)(kdot + j0);
        int b = (lane & 7) * 4;
        float e, f;
        e = kv.x + qi; f = fmaxf(e, 0.01f * e); s += ((word >> (b + 0)) & 1) ? exp2f(f) : 0.f;
        e = kv.y + qi; f = fmaxf(e, 0.01f * e); s += ((word >> (b + 1)) & 1) ? exp2f(f) : 0.f;
        e = kv.z + qi; f = fmaxf(e, 0.01f * e); s += ((word >> (b + 2)) & 1) ? exp2f(f) : 0.f;
        e = kv.w + qi; f = fmaxf(e, 0.01f * e); s += ((word >> (b + 3)) & 1) ? exp2f(f) : 0.f;
    }
#pragma unroll
    for (int o = 32; o; o >>= 1) s += __shfl_xor(s, o);
    if (lane == 0) coef[row] = (s > 0.f) ? 1.0f / s : 0.f;
}

// ---------------------------------------------------------------- pass B: pipelined masked-weighted GEMM
#define BJ 128
#define KC 64
#define NSPLIT 8
#define NCH ((NN / NSPLIT) / KC)

__launch_bounds__(256, 2)
__global__ void k_attn_gemm(const unsigned* __restrict__ bm32, const float* __restrict__ kdot,
                            const float* __restrict__ qdot, const float* __restrict__ coef,
                            const unsigned short* __restrict__ gmT,
                            float* __restrict__ dst, int use_atomic) {
    int id = blockIdx.x;
    int sp = id & 7;          // XCD-local i-split
    int jb = id >> 3;
    int j0 = jb * BJ;
    int ibase = sp * (NN / NSPLIT);
    int tid = threadIdx.x;
    int lane = tid & 63;
    int w = tid >> 6;

    __shared__ __align__(16) unsigned short A_l[BJ * KC];
    __shared__ __align__(16) unsigned short G_l[2][HIDD * KC];
    __shared__ unsigned mask_l[2][256];
    __shared__ float q_l[2][KC];
    __shared__ float c_l[2][KC];
    __shared__ float kdot_l[BJ];

    if (tid < BJ) kdot_l[tid] = kdot[j0 + tid];

    int jq0 = j0 >> 5;
    int4 greg[4];
    unsigned mreg;
    float qreg, creg;

    // ---- stage chunk 0 directly
    {
        int ig = ibase;
#pragma unroll
        for (int r = 0; r < 4; r++) {
            int slot = r * 256 + tid;
            int hh = slot >> 3, sd = slot & 7;
            greg[r] = *(const int4*)(gmT + (size_t)hh * NN + ig + sd * 8);
        }
        mreg = bm32[(size_t)(ig + lane) * 256 + jq0 + w];
        qreg = qdot[ig + lane];
        creg = coef[ig + lane];
#pragma unroll
        for (int r = 0; r < 4; r++) {
            int slot = r * 256 + tid;
            int hh = slot >> 3, sd = slot & 7;
            *(int4*)&G_l[0][hh * KC + ((sd ^ (hh & 7)) * 8)] = greg[r];
        }
        mask_l[0][tid] = mreg;
        if (tid < KC) { q_l[0][tid] = qreg; c_l[0][tid] = creg; }
    }
    __syncthreads();

    f32x4 acc[2][8];
#pragma unroll
    for (int a = 0; a < 2; a++)
#pragma unroll
        for (int b = 0; b < 8; b++) acc[a][b] = (f32x4){0.f, 0.f, 0.f, 0.f};

    int cur = 0;
    for (int c = 0; c < NCH; c++) {
        // 1. issue next-chunk global loads
        if (c + 1 < NCH) {
            int ig = ibase + (c + 1) * KC;
#pragma unroll
            for (int r = 0; r < 4; r++) {
                int slot = r * 256 + tid;
                int hh = slot >> 3, sd = slot & 7;
                greg[r] = *(const int4*)(gmT + (size_t)hh * NN + ig + sd * 8);
            }
            mreg = bm32[(size_t)(ig + lane) * 256 + jq0 + w];
            qreg = qdot[ig + lane];
            creg = coef[ig + lane];
        }
        // 2. A-fill chunk c (log2-domain, coef folded, packed pairs)
#pragma unroll 4
        for (int rep = 0; rep < 16; rep++) {
            int idx = rep * 256 + tid;
            int j = idx >> 5;
            int i0 = (idx & 31) * 2;
            uint2 wds = *(const uint2*)&mask_l[cur][(j >> 5) * KC + i0];
            float2 qv = *(const float2*)&q_l[cur][i0];
            float2 cc = *(const float2*)&c_l[cur][i0];
            float kd = kdot_l[j];
            int bit = j & 31;
            float e0 = kd + qv.x, f0 = fmaxf(e0, 0.01f * e0);
            float e1 = kd + qv.y, f1 = fmaxf(e1, 0.01f * e1);
            float w0 = ((wds.x >> bit) & 1) ? exp2f(f0) * cc.x : 0.f;
            float w1 = ((wds.y >> bit) & 1) ? exp2f(f1) * cc.y : 0.f;
            unsigned pk = ((unsigned)f2b(w1) << 16) | (unsigned)f2b(w0);
            int dcol = (((i0 >> 3) ^ (j & 7)) * 8) | (i0 & 7);
            *(unsigned*)&A_l[j * KC + dcol] = pk;
        }
        __syncthreads();
        // 3. MFMA on chunk c
        __builtin_amdgcn_s_setprio(1);
#pragma unroll
        for (int kk = 0; kk < 2; kk++) {
            int kb = kk * 32 + (lane >> 4) * 8;
            int r0 = w * 32 + (lane & 15);
            int r1 = r0 + 16;
            bf16x8 a0 = *(const bf16x8*)&A_l[r0 * KC + (kb ^ ((r0 & 7) << 3))];
            bf16x8 a1v = *(const bf16x8*)&A_l[r1 * KC + (kb ^ ((r1 & 7) << 3))];
#pragma unroll
            for (int hf = 0; hf < 8; hf++) {
                int hr = hf * 16 + (lane & 15);
                bf16x8 bv = *(const bf16x8*)&G_l[cur][hr * KC + (kb ^ ((hr & 7) << 3))];
                acc[0][hf] = __builtin_amdgcn_mfma_f32_16x16x32_bf16(a0, bv, acc[0][hf], 0, 0, 0);
                acc[1][hf] = __builtin_amdgcn_mfma_f32_16x16x32_bf16(a1v, bv, acc[1][hf], 0, 0, 0);
            }
        }
        __builtin_amdgcn_s_setprio(0);
        // 4. write staged regs into the other buffer
        if (c + 1 < NCH) {
            int nxt = cur ^ 1;
#pragma unroll
            for (int r = 0; r < 4; r++) {
                int slot = r * 256 + tid;
                int hh = slot >> 3, sd = slot & 7;
                *(int4*)&G_l[nxt][hh * KC + ((sd ^ (hh & 7)) * 8)] = greg[r];
            }
            mask_l[nxt][tid] = mreg;
            if (tid < KC) { q_l[nxt][tid] = qreg; c_l[nxt][tid] = creg; }
        }
        __syncthreads();
        cur ^= 1;
    }
    // epilogue
    int row_base = w * 32 + (lane >> 4) * 4;
    int col = lane & 15;
    size_t slab = use_atomic ? 0 : (size_t)sp * NN * HIDD;
#pragma unroll
    for (int jf = 0; jf < 2; jf++)
#pragma unroll
        for (int hf = 0; hf < 8; hf++)
#pragma unroll
            for (int r = 0; r < 4; r++) {
                int j = j0 + row_base + jf * 16 + r;
                int hcol = hf * 16 + col;
                size_t off = (size_t)j * HIDD + hcol;
                if (use_atomic) atomicAdd(&dst[off], acc[jf][hf][r]);
                else dst[slab + off] = acc[jf][hf][r];
            }
}

// ---------------------------------------------------------------- final combine + loss
__global__ void k_combine(const float* __restrict__ acc, int nslab,
                          const float* __restrict__ hin, float* __restrict__ hout,
                          const float* __restrict__ lossacc, float* __restrict__ lossout) {
    size_t i = (size_t)blockIdx.x * blockDim.x + threadIdx.x;
    float4 hv = ((const float4*)hin)[i];
    float sx = 0.f, sy = 0.f, sz = 0.f, sw = 0.f;
    for (int s = 0; s < nslab; s++) {
        float4 a = ((const float4*)(acc + (size_t)s * NN * HIDD))[i];
        sx += a.x; sy += a.y; sz += a.z; sw += a.w;
    }
    float4 o;
    o.x = (sx + hv.x) * 0.5f;
    o.y = (sy + hv.y) * 0.5f;
    o.z = (sz + hv.z) * 0.5f;
    o.w = (sw + hv.w) * 0.5f;
    ((float4*)hout)[i] = o;
    if (i == 0)
        lossout[0] = lossacc[0] * (1.0f / (float)((size_t)NN * HIDD * NLAY));
}

// ================================================================ host
extern "C" void kernel_launch(void* const* d_in, const int* in_sizes, int n_in,
                              void* d_out, int out_size, void* d_ws, size_t ws_size,
                              hipStream_t stream) {
    const float* h_in = (const float*)d_in[0];
    const int* adj = (const int*)d_in[1];
    const float* z = (const float*)d_in[2];
    const float* Wp = (const float*)d_in[3];
    const float* bp = (const float*)d_in[4];
    const float* Wm = (const float*)d_in[5];
    const float* bmv = (const float*)d_in[6];
    const float* Wg = (const float*)d_in[7];
    const float* bgv = (const float*)d_in[8];
    const float* Wk = (const float*)d_in[9];
    const float* bk = (const float*)d_in[10];
    const float* Wq = (const float*)d_in[11];
    const float* bq = (const float*)d_in[12];
    const float* a1 = (const float*)d_in[13];
    const float* a2 = (const float*)d_in[14];
    float* out = (float*)d_out;

    char* ws = (char*)d_ws;
    unsigned long long* BM64 = (unsigned long long*)(ws + 0);          // 8 MB
    unsigned* BM32 = (unsigned*)(ws + 0);
    float* hcur = (float*)(ws + (8ull << 20));                         // 4 MB
    unsigned short* gmT = (unsigned short*)(ws + (16ull << 20));       // 2 MB
    float* kdot = (float*)(ws + (18ull << 20));
    float* qdot = (float*)(ws + (18ull << 20) + (32ull << 10));
    float* coef = (float*)(ws + (18ull << 20) + (64ull << 10));
    float* wka = (float*)(ws + (18ull << 20) + (96ull << 10));
    float* wqa = (float*)(ws + (18ull << 20) + (100ull << 10));
    float* scal = (float*)(ws + (18ull << 20) + (104ull << 10));
    float* lossacc = (float*)(ws + (18ull << 20) + (108ull << 10));
    float* agg = (float*)(ws + (19ull << 20));                         // 4 MB
    float* part = (float*)(ws + (23ull << 20));                        // 8 x 4 MB
    int use_atomic = (ws_size < (56ull << 20)) ? 1 : 0;
    float* dst = use_atomic ? agg : part;
    int nslab = use_atomic ? 1 : NSPLIT;

    hipMemsetAsync(lossacc, 0, 4, stream);
    k_pre<<<2048, 256, 0, stream>>>(adj, BM64, h_in, Wp, bp, hcur,
                                    Wk, Wq, a1, a2, bk, bq, wka, wqa, scal);

    for (int l = 0; l < NLAY; l++) {
        k_gm<<<NN / 16, 256, 0, stream>>>(
            hcur, (l > 0) ? dst : nullptr, (l > 0) ? nslab : 0, hcur,
            z, Wm + (size_t)l * 128 * 128, bmv + l * 128,
            Wg + (size_t)l * 192 * 128, bgv + l * 128,
            wka + l * 128, wqa + l * 128, scal + l * 2,
            gmT, kdot, qdot, lossacc);
        k_stats<<<NN / 4, 256, 0, stream>>>(BM32, kdot, qdot, coef);
        if (use_atomic) hipMemsetAsync(agg, 0, (size_t)NN * HIDD * 4, stream);
        k_attn_gemm<<<(NN / BJ) * NSPLIT, 256, 0, stream>>>(BM32, kdot, qdot, coef, gmT, dst, use_atomic);
    }
    k_combine<<<NN * HIDD / 4 / 256, 256, 0, stream>>>(
        dst, nslab, hcur, out, lossacc, out + (size_t)NN * HIDD);
}

// Round 5
// 310.142 us; speedup vs baseline: 1.0776x; 1.0776x over previous
//
#include <hip/hip_runtime.h>
#include <hip/hip_bf16.h>

#define NN 8192
#define HIDD 128
#define NLAY 2

typedef __attribute__((ext_vector_type(8))) short bf16x8;
typedef __attribute__((ext_vector_type(4))) float f32x4;

static __device__ __forceinline__ unsigned short f2b(float x) {
    __hip_bfloat16 h = __float2bfloat16(x);
    return *reinterpret_cast<unsigned short*>(&h);
}

// spread bit i -> bit 4i (16-bit input)
static __device__ __forceinline__ unsigned long long spread4(unsigned long long x) {
    x = (x | (x << 24)) & 0x000000ff000000ffULL;
    x = (x | (x << 12)) & 0x000f000f000f000fULL;
    x = (x | (x << 6))  & 0x0303030303030303ULL;
    x = (x | (x << 3))  & 0x1111111111111111ULL;
    return x;
}

// ================================================================ pre-kernel
// blocks 0..511: proj (16 rows each); 512..513: wprep (l = b-512); rest: bitmask
__global__ void k_pre(const int* __restrict__ adj, unsigned long long* __restrict__ bm,
                      const float* __restrict__ hin, const float* __restrict__ Wp,
                      const float* __restrict__ bp, float* __restrict__ hout,
                      const float* __restrict__ Wk, const float* __restrict__ Wq,
                      const float* __restrict__ a1, const float* __restrict__ a2,
                      const float* __restrict__ bk, const float* __restrict__ bq,
                      float* __restrict__ wka, float* __restrict__ wqa,
                      float* __restrict__ scal) {
    __shared__ float ht[16][128];
    int b = blockIdx.x;
    int tid = threadIdx.x;
    if (b < 512) {
        // ---- proj: h0 = h @ Wp + bp
        int i0 = b * 16;
#pragma unroll
        for (int r = 0; r < 2; r++) {
            int q = r * 256 + tid;
            ((float4*)ht)[q] = ((const float4*)(hin + (size_t)i0 * 128))[q];
        }
        __syncthreads();
        int c = tid & 127, half = tid >> 7;
        float acc[8];
        float b0 = bp[c];
#pragma unroll
        for (int m = 0; m < 8; m++) acc[m] = b0;
        for (int k = 0; k < 128; k += 4) {
            float w0 = Wp[k * 128 + c], w1 = Wp[(k + 1) * 128 + c];
            float w2 = Wp[(k + 2) * 128 + c], w3 = Wp[(k + 3) * 128 + c];
#pragma unroll
            for (int m = 0; m < 8; m++) {
                float4 hv = *(const float4*)&ht[half + 2 * m][k];
                acc[m] = fmaf(hv.x, w0, acc[m]);
                acc[m] = fmaf(hv.y, w1, acc[m]);
                acc[m] = fmaf(hv.z, w2, acc[m]);
                acc[m] = fmaf(hv.w, w3, acc[m]);
            }
        }
#pragma unroll
        for (int m = 0; m < 8; m++) hout[(size_t)(i0 + half + 2 * m) * 128 + c] = acc[m];
    } else if (b < 514) {
        // ---- wprep for layer l
        int l = b - 512;
        const float* a1L = a1 + l * 128;
        const float* a2L = a2 + l * 128;
        if (tid < 128) {
            const float* W1 = Wk + (size_t)l * 16384 + (size_t)tid * 128;
            const float* W2 = Wq + (size_t)l * 16384 + (size_t)tid * 128;
            float s1 = 0.f, s2 = 0.f;
            for (int c = 0; c < 128; c++) {
                s1 = fmaf(W1[c], a1L[c], s1);
                s2 = fmaf(W2[c], a2L[c], s2);
            }
            wka[l * 128 + tid] = s1;
            wqa[l * 128 + tid] = s2;
        } else if (tid == 128) {
            float s = 0.f;
            for (int c = 0; c < 128; c++) s = fmaf(bk[l * 128 + c], a1L[c], s);
            scal[l * 2 + 0] = s;
        } else if (tid == 129) {
            float s = 0.f;
            for (int c = 0; c < 128; c++) s = fmaf(bq[l * 128 + c], a2L[c], s);
            scal[l * 2 + 1] = s;
        }
    } else {
        // ---- bitmask (16B/lane)
        const long totalg = (long)NN * (NN / 256);
        int lane = tid & 63, w = tid >> 6;
        long nb = (long)gridDim.x - 514;
        long g = (long)(b - 514) * 4 + w;
        long ng = nb * 4;
        for (; g < totalg; g += ng) {
            int4 v = ((const int4*)adj)[g * 64 + lane];
            unsigned long long B0 = __ballot(v.x > 0);
            unsigned long long B1 = __ballot(v.y > 0);
            unsigned long long B2 = __ballot(v.z > 0);
            unsigned long long B3 = __ballot(v.w > 0);
            if (lane < 4) {
                int sh = lane * 16;
                unsigned long long W = spread4((B0 >> sh) & 0xFFFF)
                                     | (spread4((B1 >> sh) & 0xFFFF) << 1)
                                     | (spread4((B2 >> sh) & 0xFFFF) << 2)
                                     | (spread4((B3 >> sh) & 0xFFFF) << 3);
                bm[g * 4 + lane] = W;
            }
        }
    }
}

// ================================================================ fused gm
__global__ void k_gm(const float* __restrict__ hbase, const float* __restrict__ aggs, int nslab,
                     float* __restrict__ hstore, const float* __restrict__ z,
                     const float* __restrict__ Wm, const float* __restrict__ bmv,
                     const float* __restrict__ Wg, const float* __restrict__ bgv,
                     const float* __restrict__ wka, const float* __restrict__ wqa,
                     const float* __restrict__ scal,
                     unsigned short* __restrict__ gmT, float* __restrict__ kdot,
                     float* __restrict__ qdot, float* __restrict__ lossacc) {
    __shared__ float ht[16][128];
    __shared__ float zt[16][64];
    __shared__ unsigned short tb[128][24];
    __shared__ float redk[4][8], redq[4][8], redl[4];
    int i0 = blockIdx.x * 16;
    int tid = threadIdx.x;
#pragma unroll
    for (int r = 0; r < 2; r++) {
        int q = r * 256 + tid;
        float4 hv = ((const float4*)(hbase + (size_t)i0 * 128))[q];
        if (nslab > 0) {
            float sx = 0.f, sy = 0.f, sz = 0.f, sw = 0.f;
            for (int s = 0; s < nslab; s++) {
                float4 a = ((const float4*)(aggs + (size_t)s * NN * HIDD + (size_t)i0 * 128))[q];
                sx += a.x; sy += a.y; sz += a.z; sw += a.w;
            }
            hv.x = (hv.x + sx) * 0.5f;
            hv.y = (hv.y + sy) * 0.5f;
            hv.z = (hv.z + sz) * 0.5f;
            hv.w = (hv.w + sw) * 0.5f;
            ((float4*)(hstore + (size_t)i0 * 128))[q] = hv;
        }
        ((float4*)ht)[q] = hv;
    }
    ((float4*)zt)[tid] = ((const float4*)(z + (size_t)i0 * 64))[tid];
    __syncthreads();
    int c = tid & 127, half = tid >> 7;
    float am[8], ag[8];
    float bm0 = bmv[c], bg0 = bgv[c];
#pragma unroll
    for (int m = 0; m < 8; m++) { am[m] = bm0; ag[m] = bg0; }
    for (int k = 0; k < 128; k += 4) {
        float wm0 = Wm[k * 128 + c], wm1 = Wm[(k + 1) * 128 + c];
        float wm2 = Wm[(k + 2) * 128 + c], wm3 = Wm[(k + 3) * 128 + c];
        float wg0 = Wg[k * 128 + c], wg1 = Wg[(k + 1) * 128 + c];
        float wg2 = Wg[(k + 2) * 128 + c], wg3 = Wg[(k + 3) * 128 + c];
#pragma unroll
        for (int m = 0; m < 8; m++) {
            float4 hv = *(const float4*)&ht[half + 2 * m][k];
            am[m] = fmaf(hv.x, wm0, am[m]);
            am[m] = fmaf(hv.y, wm1, am[m]);
            am[m] = fmaf(hv.z, wm2, am[m]);
            am[m] = fmaf(hv.w, wm3, am[m]);
            ag[m] = fmaf(hv.x, wg0, ag[m]);
            ag[m] = fmaf(hv.y, wg1, ag[m]);
            ag[m] = fmaf(hv.z, wg2, ag[m]);
            ag[m] = fmaf(hv.w, wg3, ag[m]);
        }
    }
    for (int k = 0; k < 64; k += 4) {
        float wg0 = Wg[(128 + k) * 128 + c], wg1 = Wg[(129 + k) * 128 + c];
        float wg2 = Wg[(130 + k) * 128 + c], wg3 = Wg[(131 + k) * 128 + c];
#pragma unroll
        for (int m = 0; m < 8; m++) {
            float4 zv = *(const float4*)&zt[half + 2 * m][k];
            ag[m] = fmaf(zv.x, wg0, ag[m]);
            ag[m] = fmaf(zv.y, wg1, ag[m]);
            ag[m] = fmaf(zv.z, wg2, ag[m]);
            ag[m] = fmaf(zv.w, wg3, ag[m]);
        }
    }
    float lsum = 0.f;
    float gmv[8];
#pragma unroll
    for (int m = 0; m < 8; m++) {
        float gate = 1.f / (1.f + __expf(-ag[m]));
        lsum += gate;
        gmv[m] = gate * fmaxf(am[m], 0.f);
        tb[c][half + 2 * m] = f2b(gmv[m]);
    }
    float wkac = wka[c], wqac = wqa[c];
    int wid = tid >> 6, lane = tid & 63;
#pragma unroll
    for (int m = 0; m < 8; m++) {
        float vk = ht[half + 2 * m][c] * wkac;
        float vq = gmv[m] * wqac;
#pragma unroll
        for (int o = 32; o; o >>= 1) {
            vk += __shfl_down(vk, o);
            vq += __shfl_down(vq, o);
        }
        if (lane == 0) { redk[wid][m] = vk; redq[wid][m] = vq; }
    }
#pragma unroll
    for (int o = 32; o; o >>= 1) lsum += __shfl_down(lsum, o);
    if (lane == 0) redl[wid] = lsum;
    __syncthreads();
    if (tid < 16) {
        int r = tid, hf = r & 1, m = r >> 1;
        const float LOG2E = 1.4426950408889634f;
        kdot[i0 + r] = (redk[2 * hf][m] + redk[2 * hf + 1][m] + scal[0]) * LOG2E;
        qdot[i0 + r] = (redq[2 * hf][m] + redq[2 * hf + 1][m] + scal[1]) * LOG2E;
    }
    if (tid == 0) atomicAdd(lossacc, redl[0] + redl[1] + redl[2] + redl[3]);
    int hh = tid >> 1, io = (tid & 1) * 8;
    *(int4*)&gmT[(size_t)hh * NN + i0 + io] = *(int4*)&tb[hh][io];
}

// ---------------------------------------------------------------- coef[i]
__global__ void k_stats(const unsigned* __restrict__ bm32, const float* __restrict__ kdot,
                        const float* __restrict__ qdot, float* __restrict__ coef) {
    int row = (int)((blockIdx.x * blockDim.x + threadIdx.x) >> 6);
    int lane = threadIdx.x & 63;
    const unsigned* bmr = bm32 + (size_t)row * 256;
    float qi = qdot[row];
    float s = 0.f;
    for (int t = 0; t < 32; t++) {
        int j0 = t * 256 + lane * 4;
        unsigned word = bmr[j0 >> 5];
        float4 kv = *(const float4*)(kdot + j0);
        int b = (lane & 7) * 4;
        float e, f;
        e = kv.x + qi; f = fmaxf(e, 0.01f * e); s += ((word >> (b + 0)) & 1) ? exp2f(f) : 0.f;
        e = kv.y + qi; f = fmaxf(e, 0.01f * e); s += ((word >> (b + 1)) & 1) ? exp2f(f) : 0.f;
        e = kv.z + qi; f = fmaxf(e, 0.01f * e); s += ((word >> (b + 2)) & 1) ? exp2f(f) : 0.f;
        e = kv.w + qi; f = fmaxf(e, 0.01f * e); s += ((word >> (b + 3)) & 1) ? exp2f(f) : 0.f;
    }
#pragma unroll
    for (int o = 32; o; o >>= 1) s += __shfl_xor(s, o);
    if (lane == 0) coef[row] = (s > 0.f) ? 1.0f / s : 0.f;
}

// ---------------------------------------------------------------- pass B: A-in-registers
#define BJ 128
#define KC 64
#define NSPLIT 8
#define NCH ((NN / NSPLIT) / KC)

__launch_bounds__(256, 2)
__global__ void k_attn_gemm(const unsigned* __restrict__ bm32, const float* __restrict__ kdot,
                            const float* __restrict__ qdot, const float* __restrict__ coef,
                            const unsigned short* __restrict__ gmT,
                            float* __restrict__ dst, int use_atomic) {
    int id = blockIdx.x;
    int sp = id & 7;
    int jb = id >> 3;
    int j0 = jb * BJ;
    int ibase = sp * (NN / NSPLIT);
    int tid = threadIdx.x;
    int lane = tid & 63;
    int w = tid >> 6;
    int lo = lane & 15;
    int qw = lane >> 4;

    __shared__ __align__(16) unsigned short G_l[2][HIDD * KC];
    __shared__ __align__(16) unsigned mask_l[2][4 * KC];
    __shared__ __align__(16) float q_l[2][KC];
    __shared__ __align__(16) float c_l[2][KC];

    // per-lane row constants (log2-prescaled kdot)
    float kd0 = kdot[j0 + w * 32 + lo];
    float kd1 = kdot[j0 + w * 32 + lo + 16];

    int jq0 = j0 >> 5;
    int4 greg[4];
    unsigned mreg;
    float qreg, creg;

    // ---- stage chunk 0 directly
    {
        int ig = ibase;
#pragma unroll
        for (int r = 0; r < 4; r++) {
            int slot = r * 256 + tid;
            int hh = slot >> 3, sd = slot & 7;
            greg[r] = *(const int4*)(gmT + (size_t)hh * NN + ig + sd * 8);
        }
        mreg = bm32[(size_t)(ig + lane) * 256 + jq0 + w];
        qreg = qdot[ig + lane];
        creg = coef[ig + lane];
#pragma unroll
        for (int r = 0; r < 4; r++) {
            int slot = r * 256 + tid;
            int hh = slot >> 3, sd = slot & 7;
            *(int4*)&G_l[0][hh * KC + ((sd ^ (hh & 7)) * 8)] = greg[r];
        }
        mask_l[0][tid] = mreg;
        if (tid < KC) { q_l[0][tid] = qreg; c_l[0][tid] = creg; }
    }
    __syncthreads();

    f32x4 acc[2][8];
#pragma unroll
    for (int a = 0; a < 2; a++)
#pragma unroll
        for (int b = 0; b < 8; b++) acc[a][b] = (f32x4){0.f, 0.f, 0.f, 0.f};

    int cur = 0;
    for (int c = 0; c < NCH; c++) {
        // 1. issue next-chunk global loads (consumed at step 4)
        if (c + 1 < NCH) {
            int ig = ibase + (c + 1) * KC;
#pragma unroll
            for (int r = 0; r < 4; r++) {
                int slot = r * 256 + tid;
                int hh = slot >> 3, sd = slot & 7;
                greg[r] = *(const int4*)(gmT + (size_t)hh * NN + ig + sd * 8);
            }
            mreg = bm32[(size_t)(ig + lane) * 256 + jq0 + w];
            qreg = qdot[ig + lane];
            creg = coef[ig + lane];
        }
        // 2+3. per-kk: A-fragment in registers, then MFMA
#pragma unroll
        for (int kk = 0; kk < 2; kk++) {
            int kb = kk * 32 + qw * 8;
            float4 qa = *(const float4*)&q_l[cur][kb];
            float4 qb = *(const float4*)&q_l[cur][kb + 4];
            float4 ca = *(const float4*)&c_l[cur][kb];
            float4 cb = *(const float4*)&c_l[cur][kb + 4];
            uint4 ma = *(const uint4*)&mask_l[cur][w * 64 + kb];
            uint4 mb = *(const uint4*)&mask_l[cur][w * 64 + kb + 4];
            float qv[8] = {qa.x, qa.y, qa.z, qa.w, qb.x, qb.y, qb.z, qb.w};
            float cv[8] = {ca.x, ca.y, ca.z, ca.w, cb.x, cb.y, cb.z, cb.w};
            unsigned mw[8] = {ma.x, ma.y, ma.z, ma.w, mb.x, mb.y, mb.z, mb.w};
            union { unsigned u[4]; bf16x8 v; } A0, A1;
#pragma unroll
            for (int p = 0; p < 4; p++) {
                float w00, w01, w10, w11;
                {
                    int e = 2 * p;
                    float x0 = kd0 + qv[e], x1 = kd1 + qv[e];
                    float f0 = fmaxf(x0, 0.01f * x0) ;
                    float f1 = fmaxf(x1, 0.01f * x1);
                    float v0 = exp2f(f0) * cv[e], v1 = exp2f(f1) * cv[e];
                    w00 = ((mw[e] >> lo) & 1) ? v0 : 0.f;
                    w10 = ((mw[e] >> (lo + 16)) & 1) ? v1 : 0.f;
                }
                {
                    int e = 2 * p + 1;
                    float x0 = kd0 + qv[e], x1 = kd1 + qv[e];
                    float f0 = fmaxf(x0, 0.01f * x0);
                    float f1 = fmaxf(x1, 0.01f * x1);
                    float v0 = exp2f(f0) * cv[e], v1 = exp2f(f1) * cv[e];
                    w01 = ((mw[e] >> lo) & 1) ? v0 : 0.f;
                    w11 = ((mw[e] >> (lo + 16)) & 1) ? v1 : 0.f;
                }
                A0.u[p] = (unsigned)f2b(w00) | ((unsigned)f2b(w01) << 16);
                A1.u[p] = (unsigned)f2b(w10) | ((unsigned)f2b(w11) << 16);
            }
            __builtin_amdgcn_s_setprio(1);
#pragma unroll
            for (int hf = 0; hf < 8; hf++) {
                int hr = hf * 16 + lo;
                bf16x8 bv = *(const bf16x8*)&G_l[cur][hr * KC + ((kk * 32 + qw * 8) ^ ((hr & 7) << 3))];
                acc[0][hf] = __builtin_amdgcn_mfma_f32_16x16x32_bf16(A0.v, bv, acc[0][hf], 0, 0, 0);
                acc[1][hf] = __builtin_amdgcn_mfma_f32_16x16x32_bf16(A1.v, bv, acc[1][hf], 0, 0, 0);
            }
            __builtin_amdgcn_s_setprio(0);
        }
        // 4. write staged regs into the other buffer
        if (c + 1 < NCH) {
            int nxt = cur ^ 1;
#pragma unroll
            for (int r = 0; r < 4; r++) {
                int slot = r * 256 + tid;
                int hh = slot >> 3, sd = slot & 7;
                *(int4*)&G_l[nxt][hh * KC + ((sd ^ (hh & 7)) * 8)] = greg[r];
            }
            mask_l[nxt][tid] = mreg;
            if (tid < KC) { q_l[nxt][tid] = qreg; c_l[nxt][tid] = creg; }
        }
        __syncthreads();   // staged [nxt] visible; all reads of [cur] complete
        cur ^= 1;
    }
    // epilogue
    int row_base = w * 32 + (lane >> 4) * 4;
    int col = lane & 15;
    size_t slab = use_atomic ? 0 : (size_t)sp * NN * HIDD;
#pragma unroll
    for (int jf = 0; jf < 2; jf++)
#pragma unroll
        for (int hf = 0; hf < 8; hf++)
#pragma unroll
            for (int r = 0; r < 4; r++) {
                int j = j0 + row_base + jf * 16 + r;
                int hcol = hf * 16 + col;
                size_t off = (size_t)j * HIDD + hcol;
                if (use_atomic) atomicAdd(&dst[off], acc[jf][hf][r]);
                else dst[slab + off] = acc[jf][hf][r];
            }
}

// ---------------------------------------------------------------- final combine + loss
__global__ void k_combine(const float* __restrict__ acc, int nslab,
                          const float* __restrict__ hin, float* __restrict__ hout,
                          const float* __restrict__ lossacc, float* __restrict__ lossout) {
    size_t i = (size_t)blockIdx.x * blockDim.x + threadIdx.x;
    float4 hv = ((const float4*)hin)[i];
    float sx = 0.f, sy = 0.f, sz = 0.f, sw = 0.f;
    for (int s = 0; s < nslab; s++) {
        float4 a = ((const float4*)(acc + (size_t)s * NN * HIDD))[i];
        sx += a.x; sy += a.y; sz += a.z; sw += a.w;
    }
    float4 o;
    o.x = (sx + hv.x) * 0.5f;
    o.y = (sy + hv.y) * 0.5f;
    o.z = (sz + hv.z) * 0.5f;
    o.w = (sw + hv.w) * 0.5f;
    ((float4*)hout)[i] = o;
    if (i == 0)
        lossout[0] = lossacc[0] * (1.0f / (float)((size_t)NN * HIDD * NLAY));
}

// ================================================================ host
extern "C" void kernel_launch(void* const* d_in, const int* in_sizes, int n_in,
                              void* d_out, int out_size, void* d_ws, size_t ws_size,
                              hipStream_t stream) {
    const float* h_in = (const float*)d_in[0];
    const int* adj = (const int*)d_in[1];
    const float* z = (const float*)d_in[2];
    const float* Wp = (const float*)d_in[3];
    const float* bp = (const float*)d_in[4];
    const float* Wm = (const float*)d_in[5];
    const float* bmv = (const float*)d_in[6];
    const float* Wg = (const float*)d_in[7];
    const float* bgv = (const float*)d_in[8];
    const float* Wk = (const float*)d_in[9];
    const float* bk = (const float*)d_in[10];
    const float* Wq = (const float*)d_in[11];
    const float* bq = (const float*)d_in[12];
    const float* a1 = (const float*)d_in[13];
    const float* a2 = (const float*)d_in[14];
    float* out = (float*)d_out;

    char* ws = (char*)d_ws;
    unsigned long long* BM64 = (unsigned long long*)(ws + 0);          // 8 MB
    unsigned* BM32 = (unsigned*)(ws + 0);
    float* hcur = (float*)(ws + (8ull << 20));                         // 4 MB
    unsigned short* gmT = (unsigned short*)(ws + (16ull << 20));       // 2 MB
    float* kdot = (float*)(ws + (18ull << 20));
    float* qdot = (float*)(ws + (18ull << 20) + (32ull << 10));
    float* coef = (float*)(ws + (18ull << 20) + (64ull << 10));
    float* wka = (float*)(ws + (18ull << 20) + (96ull << 10));
    float* wqa = (float*)(ws + (18ull << 20) + (100ull << 10));
    float* scal = (float*)(ws + (18ull << 20) + (104ull << 10));
    float* lossacc = (float*)(ws + (18ull << 20) + (108ull << 10));
    float* agg = (float*)(ws + (19ull << 20));                         // 4 MB
    float* part = (float*)(ws + (23ull << 20));                        // 8 x 4 MB
    int use_atomic = (ws_size < (56ull << 20)) ? 1 : 0;
    float* dst = use_atomic ? agg : part;
    int nslab = use_atomic ? 1 : NSPLIT;

    hipMemsetAsync(lossacc, 0, 4, stream);
    k_pre<<<2048, 256, 0, stream>>>(adj, BM64, h_in, Wp, bp, hcur,
                                    Wk, Wq, a1, a2, bk, bq, wka, wqa, scal);

    for (int l = 0; l < NLAY; l++) {
        k_gm<<<NN / 16, 256, 0, stream>>>(
            hcur, (l > 0) ? dst : nullptr, (l > 0) ? nslab : 0, hcur,
            z, Wm + (size_t)l * 128 * 128, bmv + l * 128,
            Wg + (size_t)l * 192 * 128, bgv + l * 128,
            wka + l * 128, wqa + l * 128, scal + l * 2,
            gmT, kdot, qdot, lossacc);
        k_stats<<<NN / 4, 256, 0, stream>>>(BM32, kdot, qdot, coef);
        if (use_atomic) hipMemsetAsync(agg, 0, (size_t)NN * HIDD * 4, stream);
        k_attn_gemm<<<(NN / BJ) * NSPLIT, 256, 0, stream>>>(BM32, kdot, qdot, coef, gmT, dst, use_atomic);
    }
    k_combine<<<NN * HIDD / 4 / 256, 256, 0, stream>>>(
        dst, nslab, hcur, out, lossacc, out + (size_t)NN * HIDD);
}